// Round 6
// baseline (62.942 us; speedup 1.0000x reference)
//
#include <hip/hip_runtime.h>
#include <hip/hip_bf16.h>
#include <hip/hip_fp16.h>
#include <math.h>

#define NB 4
#define NQ 256
#define NK 1024
#define ND 512
#define NA 128

// ws layout (bytes)
#define OFFB_H1 0u          // NB*NQ*NA f16 = 256 KB
#define OFFB_WA 262144u     // 128 f16 (0.5*Wa) = 256 B
#define OFFB_H2 524288u     // NB*NK*NA f16 = 1 MB
#define OFFB_SC 2621440u    // NB*NQ*NK bf16 = 2 MB
#define OFFB_VT 4718592u    // NB*ND*NK bf16 = 4 MB

#define PROJ_BLKS 80        // 5120 rows / 64

typedef __attribute__((ext_vector_type(8))) short short8;
typedef __attribute__((ext_vector_type(8))) unsigned short ushort8_t;
typedef __attribute__((ext_vector_type(4))) float f32x4;
typedef _Float16 half2v __attribute__((ext_vector_type(2)));

static __device__ __forceinline__ ushort f2bf(float x) {
    __hip_bfloat16 h = __float2bfloat16(x);   // RNE
    return *reinterpret_cast<ushort*>(&h);
}
static __device__ __forceinline__ half2v u2h(unsigned u) {
    union { unsigned u; half2v h; } c; c.u = u; return c.h;
}
static __device__ __forceinline__ unsigned h2u(half2v h) {
    union { half2v h; unsigned u; } c; c.h = h; return c.u;
}

// LDS address swizzle for k1 MFMA staging (write & read identically).
static __device__ __forceinline__ unsigned swz(int row, int o) {
    return (unsigned)(row * 256 + (o ^ ((row & 7) << 4) ^ (((o >> 7) & 1) << 5)));
}

// ---------------- Kernel 1: fused {MFMA projections | value transpose+cvt}
// blocks 0..79: 64 rows x 128 cols of h = X@W^T + b via bf16 MFMA, f16 out.
// blocks 80..591: vt[b][d][k] = bf16(value[b][k][d]); block 80 also emits 0.5*Wa f16.
__global__ __launch_bounds__(256) void k_proj_vt(
    const float* __restrict__ query, const float* __restrict__ key,
    const float* __restrict__ value, const float* __restrict__ Wa,
    const float* __restrict__ Wq, const float* __restrict__ bq,
    const float* __restrict__ Wk, const float* __restrict__ bk,
    __half* __restrict__ h1, __half* __restrict__ h2, __half* __restrict__ wa16,
    __hip_bfloat16* __restrict__ vt)
{
    __shared__ __align__(16) ushort smem[24576];  // 48KB: Xs 16KB @0, Ws 32KB @16384B
    char* sbytes = (char*)smem;
    const int tid = threadIdx.x;
    const int bid = blockIdx.x;

    if (bid < PROJ_BLKS) {
        const int r0 = bid * 64;
        const bool isQ = r0 < NB * NQ;
        const float* X    = isQ ? query + (size_t)r0 * ND : key + (size_t)(r0 - NB * NQ) * ND;
        const float* W    = isQ ? Wq : Wk;
        const float* bias = isQ ? bq : bk;
        __half* hout      = isQ ? h1 + (size_t)r0 * NA : h2 + (size_t)(r0 - NB * NQ) * NA;

        const int wave = tid >> 6, lane = tid & 63;
        const int l15 = lane & 15, lkb = (lane >> 4) * 16;   // k byte-offset in frag

        f32x4 acc[8] = {};

        for (int kc = 0; kc < ND; kc += 128) {
            __syncthreads();
            {   // stage X chunk: 64 rows x 128 k, f32 -> bf16, swizzled
                const int row = tid >> 2, kg = (tid & 3) * 32;
                const float* src = X + (size_t)row * ND + kc + kg;
                #pragma unroll
                for (int j = 0; j < 4; ++j) {
                    const float4 v0 = *(const float4*)(src + j * 8);
                    const float4 v1 = *(const float4*)(src + j * 8 + 4);
                    ushort8_t o;
                    o[0] = f2bf(v0.x); o[1] = f2bf(v0.y); o[2] = f2bf(v0.z); o[3] = f2bf(v0.w);
                    o[4] = f2bf(v1.x); o[5] = f2bf(v1.y); o[6] = f2bf(v1.z); o[7] = f2bf(v1.w);
                    *(ushort8_t*)(sbytes + swz(row, kg * 2 + j * 16)) = o;
                }
            }
            {   // stage W chunk: 128 cols x 128 k, f32 -> bf16, swizzled
                const int row = tid >> 1, kg = (tid & 1) * 64;
                const float* src = W + (size_t)row * ND + kc + kg;
                #pragma unroll
                for (int j = 0; j < 8; ++j) {
                    const float4 v0 = *(const float4*)(src + j * 8);
                    const float4 v1 = *(const float4*)(src + j * 8 + 4);
                    ushort8_t o;
                    o[0] = f2bf(v0.x); o[1] = f2bf(v0.y); o[2] = f2bf(v0.z); o[3] = f2bf(v0.w);
                    o[4] = f2bf(v1.x); o[5] = f2bf(v1.y); o[6] = f2bf(v1.z); o[7] = f2bf(v1.w);
                    *(ushort8_t*)(sbytes + 16384 + swz(row, kg * 2 + j * 16)) = o;
                }
            }
            __syncthreads();
            #pragma unroll
            for (int kk = 0; kk < 4; ++kk) {
                const int arow = wave * 16 + l15;
                const short8 a = *(const short8*)(sbytes + swz(arow, kk * 64 + lkb));
                #pragma unroll
                for (int ct = 0; ct < 8; ++ct) {
                    const int bcol = ct * 16 + l15;
                    const short8 b = *(const short8*)(sbytes + 16384 + swz(bcol, kk * 64 + lkb));
                    acc[ct] = __builtin_amdgcn_mfma_f32_16x16x32_bf16(a, b, acc[ct], 0, 0, 0);
                }
            }
        }

        // epilogue: C/D layout col=lane&15, row=(lane>>4)*4+r (m89-verified); f16 out
        const int orow0 = wave * 16 + (lane >> 4) * 4;
        #pragma unroll
        for (int ct = 0; ct < 8; ++ct) {
            const int col = ct * 16 + l15;
            const float bb = bias[col];
            #pragma unroll
            for (int r = 0; r < 4; ++r)
                hout[(size_t)(orow0 + r) * NA + col] = __float2half(acc[ct][r] + bb);
        }
    } else {
        if (bid == PROJ_BLKS && tid < NA)            // 0.5*Wa in f16 (for x+|x| trick)
            wa16[tid] = __float2half(0.5f * Wa[tid]);

        // value transpose + bf16 convert: 64k x 64d tile
        ushort (*tile)[65] = (ushort (*)[65])smem;
        const int id = bid - PROJ_BLKS;    // 0..511
        const int kt = id & 15;
        const int dt = (id >> 4) & 7;
        const int b  = id >> 7;
        const int k0 = kt * 64, d0 = dt * 64;
        const int tr = tid >> 4, tc4 = (tid & 15) * 4;

        #pragma unroll
        for (int p = 0; p < 4; ++p) {
            const int r = p * 16 + tr;
            const float4 v = *(const float4*)(value + ((size_t)(b * NK + k0 + r)) * ND + d0 + tc4);
            tile[r][tc4 + 0] = f2bf(v.x); tile[r][tc4 + 1] = f2bf(v.y);
            tile[r][tc4 + 2] = f2bf(v.z); tile[r][tc4 + 3] = f2bf(v.w);
        }
        __syncthreads();
        ushort* vo = (ushort*)vt;
        #pragma unroll
        for (int p = 0; p < 4; ++p) {
            const int d = p * 16 + tr;
            ushort4 o;
            o.x = tile[tc4 + 0][d]; o.y = tile[tc4 + 1][d];
            o.z = tile[tc4 + 2][d]; o.w = tile[tc4 + 3][d];
            *(ushort4*)(vo + ((size_t)(b * ND + d0 + d)) * NK + k0 + tc4) = o;
        }
    }
}

// ---------------- Kernel 2: logits + softmax -> score (bf16), packed-f16 math
// logit = sum_a Wa*relu(h1+h2) = sum_a (0.5Wa)*((x)+|x|), x=h1+h2 in f16 pairs:
// v_pk_add_f16 + v_and_b32(0x7FFF7FFF) + v_pk_add_f16 + v_dot2_f32_f16
// = 2 VALU/element (vs 3 scalar f32). h1/Wa reads are wave-uniform -> scalar.
__global__ __launch_bounds__(512) void k_logits_softmax(
    const ushort* __restrict__ h1, const ushort* __restrict__ h2,
    const ushort* __restrict__ wa16, __hip_bfloat16* __restrict__ score)
{
    __shared__ float redm[4][8];
    __shared__ float reds[4][8];
    const int tid = threadIdx.x;
    const int b = blockIdx.x >> 6;
    const int q0 = (blockIdx.x & 63) << 2;

    const uint4* __restrict__ h2b = (const uint4*)(h2 + (size_t)b * NK * NA);
    const uint4* __restrict__ h1g = (const uint4*)(h1 + (size_t)(b * NQ + q0) * NA);
    const uint4* __restrict__ wag = (const uint4*)wa16;

    float lg[4][2];
    #pragma unroll
    for (int c = 0; c < 2; ++c) {
        const int k = tid + c * 512;
        const uint4* row = h2b + (size_t)k * 16;   // 16 uint4 = 128 halfs
        float s0 = 0.f, s1 = 0.f, s2 = 0.f, s3 = 0.f;
        #pragma unroll
        for (int i = 0; i < 16; ++i) {
            const uint4 hv = row[i];               // per-lane (L2)
            const uint4 wv = wag[i];               // uniform -> s_load
            const uint4 p0 = h1g[0 * 16 + i];
            const uint4 p1 = h1g[1 * 16 + i];
            const uint4 p2 = h1g[2 * 16 + i];
            const uint4 p3 = h1g[3 * 16 + i];
            const unsigned hu[4] = {hv.x, hv.y, hv.z, hv.w};
            const unsigned wu[4] = {wv.x, wv.y, wv.z, wv.w};
            const unsigned q0u[4] = {p0.x, p0.y, p0.z, p0.w};
            const unsigned q1u[4] = {p1.x, p1.y, p1.z, p1.w};
            const unsigned q2u[4] = {p2.x, p2.y, p2.z, p2.w};
            const unsigned q3u[4] = {p3.x, p3.y, p3.z, p3.w};
            #pragma unroll
            for (int j = 0; j < 4; ++j) {
                const half2v hh = u2h(hu[j]);
                const half2v ww = u2h(wu[j]);
                {   half2v x = u2h(q0u[j]) + hh;
                    half2v y = x + u2h(h2u(x) & 0x7FFF7FFFu);
                    s0 = __builtin_amdgcn_fdot2(y, ww, s0, false); }
                {   half2v x = u2h(q1u[j]) + hh;
                    half2v y = x + u2h(h2u(x) & 0x7FFF7FFFu);
                    s1 = __builtin_amdgcn_fdot2(y, ww, s1, false); }
                {   half2v x = u2h(q2u[j]) + hh;
                    half2v y = x + u2h(h2u(x) & 0x7FFF7FFFu);
                    s2 = __builtin_amdgcn_fdot2(y, ww, s2, false); }
                {   half2v x = u2h(q3u[j]) + hh;
                    half2v y = x + u2h(h2u(x) & 0x7FFF7FFFu);
                    s3 = __builtin_amdgcn_fdot2(y, ww, s3, false); }
            }
        }
        lg[0][c] = s0; lg[1][c] = s1; lg[2][c] = s2; lg[3][c] = s3;
    }
    // +ba omitted — constant over k, cancels in softmax.

    const int wv_ = tid >> 6, ln = tid & 63;
    float mq[4];
    #pragma unroll
    for (int q = 0; q < 4; ++q) {
        float m = fmaxf(lg[q][0], lg[q][1]);
        for (int off = 32; off > 0; off >>= 1) m = fmaxf(m, __shfl_xor(m, off));
        if (ln == 0) redm[q][wv_] = m;
    }
    __syncthreads();
    #pragma unroll
    for (int q = 0; q < 4; ++q) {
        float m = redm[q][0];
        #pragma unroll
        for (int w = 1; w < 8; ++w) m = fmaxf(m, redm[q][w]);
        mq[q] = m;
    }
    #pragma unroll
    for (int q = 0; q < 4; ++q) {
        float s = 0.f;
        #pragma unroll
        for (int c = 0; c < 2; ++c) { lg[q][c] = __expf(lg[q][c] - mq[q]); s += lg[q][c]; }
        for (int off = 32; off > 0; off >>= 1) s += __shfl_xor(s, off);
        if (ln == 0) reds[q][wv_] = s;
    }
    __syncthreads();
    #pragma unroll
    for (int q = 0; q < 4; ++q) {
        float s = reds[q][0];
        #pragma unroll
        for (int w = 1; w < 8; ++w) s += reds[q][w];
        const float inv = 1.f / s;
        __hip_bfloat16* so = score + (size_t)(b * NQ + q0 + q) * NK + tid;
        #pragma unroll
        for (int c = 0; c < 2; ++c) so[c * 512] = __float2bfloat16(lg[q][c] * inv);
    }
}

// ---------------- Kernel 3: PV via MFMA bf16. BM=16 -> 512 blocks (2/CU) for
// latency hiding; wave = one 16x16 tile chain; no LDS, no barriers.
__global__ __launch_bounds__(256) void k_pv(
    const ushort* __restrict__ sc,   // [B][Q][K] bf16 bits
    const ushort* __restrict__ vt,   // [B][D][K] bf16 bits
    float* __restrict__ out)         // [B][Q][D] f32
{
    const int tid = threadIdx.x;
    const int wave = tid >> 6, lane = tid & 63;
    const int m0 = blockIdx.x * 16;
    const int n0 = blockIdx.y * 64 + wave * 16;
    const int b  = blockIdx.z;
    const int l15 = lane & 15, lk = (lane >> 4) * 8;

    const ushort* arow = sc + (size_t)(b * NQ + m0 + l15) * NK + lk;
    const ushort* brow = vt + (size_t)(b * ND + n0 + l15) * NK + lk;

    f32x4 acc = {0.f, 0.f, 0.f, 0.f};
    #pragma unroll 8
    for (int k = 0; k < NK; k += 32) {
        const short8 a = *(const short8*)(arow + k);
        const short8 v = *(const short8*)(brow + k);
        acc = __builtin_amdgcn_mfma_f32_16x16x32_bf16(a, v, acc, 0, 0, 0);
    }

    const int orow = (lane >> 4) * 4;
    #pragma unroll
    for (int r = 0; r < 4; ++r)
        out[(size_t)(b * NQ + m0 + orow + r) * ND + n0 + l15] = acc[r];
}

extern "C" void kernel_launch(void* const* d_in, const int* in_sizes, int n_in,
                              void* d_out, int out_size, void* d_ws, size_t ws_size,
                              hipStream_t stream) {
    const float* key   = (const float*)d_in[0];
    const float* query = (const float*)d_in[1];
    const float* value = (const float*)d_in[2];
    const float* Wk    = (const float*)d_in[3];
    const float* bk    = (const float*)d_in[4];
    const float* Wq    = (const float*)d_in[5];
    const float* bq    = (const float*)d_in[6];
    const float* Wa    = (const float*)d_in[7];
    // d_in[8] = ba: cancels in softmax — unused.

    char* ws = (char*)d_ws;
    __half* h1 = (__half*)(ws + OFFB_H1);
    __half* wa16 = (__half*)(ws + OFFB_WA);
    __half* h2 = (__half*)(ws + OFFB_H2);
    __hip_bfloat16* sc = (__hip_bfloat16*)(ws + OFFB_SC);
    __hip_bfloat16* vt = (__hip_bfloat16*)(ws + OFFB_VT);

    k_proj_vt<<<PROJ_BLKS + 512, 256, 0, stream>>>(query, key, value, Wa,
                                                   Wq, bq, Wk, bk, h1, h2, wa16, vt);
    k_logits_softmax<<<256, 512, 0, stream>>>((const ushort*)h1, (const ushort*)h2,
                                              (const ushort*)wa16, sc);
    k_pv<<<dim3(16, 8, 4), 256, 0, stream>>>((const ushort*)sc, (const ushort*)vt,
                                             (float*)d_out);
}

// Round 7
// 62.659 us; speedup vs baseline: 1.0045x; 1.0045x over previous
//
#include <hip/hip_runtime.h>
#include <hip/hip_bf16.h>
#include <hip/hip_fp16.h>
#include <math.h>

#define NB 4
#define NQ 256
#define NK 1024
#define ND 512
#define NA 128

// ws layout (bytes)
#define OFFB_H1 0u          // NB*NQ*NA f16 = 256 KB
#define OFFB_WA 262144u     // 128 f16 (0.5*Wa) = 256 B
#define OFFB_H2 524288u     // NB*NK*NA f16 = 1 MB
#define OFFB_SC 2621440u    // NB*NQ*NK bf16 = 2 MB
#define OFFB_VT 4718592u    // NB*ND*NK bf16 = 4 MB

#define PROJ_BLKS 80        // 5120 rows / 64

typedef __attribute__((ext_vector_type(8))) short short8;
typedef __attribute__((ext_vector_type(8))) unsigned short ushort8_t;
typedef __attribute__((ext_vector_type(4))) float f32x4;
typedef _Float16 half2v __attribute__((ext_vector_type(2)));

static __device__ __forceinline__ ushort f2bf(float x) {
    __hip_bfloat16 h = __float2bfloat16(x);   // RNE
    return *reinterpret_cast<ushort*>(&h);
}
static __device__ __forceinline__ half2v u2h(unsigned u) {
    union { unsigned u; half2v h; } c; c.u = u; return c.h;
}
static __device__ __forceinline__ unsigned h2u(half2v h) {
    union { half2v h; unsigned u; } c; c.h = h; return c.u;
}

// LDS address swizzle for k1 MFMA staging (write & read identically).
static __device__ __forceinline__ unsigned swz(int row, int o) {
    return (unsigned)(row * 256 + (o ^ ((row & 7) << 4) ^ (((o >> 7) & 1) << 5)));
}

// ---------------- Kernel 1: fused {MFMA projections | value transpose+cvt}
// blocks 0..79: 64 rows x 128 cols of h = X@W^T + b via bf16 MFMA, f16 out.
// blocks 80..591: vt[b][d][k] = bf16(value[b][k][d]); block 80 also emits 0.5*Wa f16.
__global__ __launch_bounds__(256) void k_proj_vt(
    const float* __restrict__ query, const float* __restrict__ key,
    const float* __restrict__ value, const float* __restrict__ Wa,
    const float* __restrict__ Wq, const float* __restrict__ bq,
    const float* __restrict__ Wk, const float* __restrict__ bk,
    __half* __restrict__ h1, __half* __restrict__ h2, __half* __restrict__ wa16,
    __hip_bfloat16* __restrict__ vt)
{
    __shared__ __align__(16) ushort smem[24576];  // 48KB: Xs 16KB @0, Ws 32KB @16384B
    char* sbytes = (char*)smem;
    const int tid = threadIdx.x;
    const int bid = blockIdx.x;

    if (bid < PROJ_BLKS) {
        const int r0 = bid * 64;
        const bool isQ = r0 < NB * NQ;
        const float* X    = isQ ? query + (size_t)r0 * ND : key + (size_t)(r0 - NB * NQ) * ND;
        const float* W    = isQ ? Wq : Wk;
        const float* bias = isQ ? bq : bk;
        __half* hout      = isQ ? h1 + (size_t)r0 * NA : h2 + (size_t)(r0 - NB * NQ) * NA;

        const int wave = tid >> 6, lane = tid & 63;
        const int l15 = lane & 15, lkb = (lane >> 4) * 16;   // k byte-offset in frag

        f32x4 acc[8] = {};

        for (int kc = 0; kc < ND; kc += 128) {
            __syncthreads();
            {   // stage X chunk: 64 rows x 128 k, f32 -> bf16, swizzled
                const int row = tid >> 2, kg = (tid & 3) * 32;
                const float* src = X + (size_t)row * ND + kc + kg;
                #pragma unroll
                for (int j = 0; j < 4; ++j) {
                    const float4 v0 = *(const float4*)(src + j * 8);
                    const float4 v1 = *(const float4*)(src + j * 8 + 4);
                    ushort8_t o;
                    o[0] = f2bf(v0.x); o[1] = f2bf(v0.y); o[2] = f2bf(v0.z); o[3] = f2bf(v0.w);
                    o[4] = f2bf(v1.x); o[5] = f2bf(v1.y); o[6] = f2bf(v1.z); o[7] = f2bf(v1.w);
                    *(ushort8_t*)(sbytes + swz(row, kg * 2 + j * 16)) = o;
                }
            }
            {   // stage W chunk: 128 cols x 128 k, f32 -> bf16, swizzled
                const int row = tid >> 1, kg = (tid & 1) * 64;
                const float* src = W + (size_t)row * ND + kc + kg;
                #pragma unroll
                for (int j = 0; j < 8; ++j) {
                    const float4 v0 = *(const float4*)(src + j * 8);
                    const float4 v1 = *(const float4*)(src + j * 8 + 4);
                    ushort8_t o;
                    o[0] = f2bf(v0.x); o[1] = f2bf(v0.y); o[2] = f2bf(v0.z); o[3] = f2bf(v0.w);
                    o[4] = f2bf(v1.x); o[5] = f2bf(v1.y); o[6] = f2bf(v1.z); o[7] = f2bf(v1.w);
                    *(ushort8_t*)(sbytes + 16384 + swz(row, kg * 2 + j * 16)) = o;
                }
            }
            __syncthreads();
            #pragma unroll
            for (int kk = 0; kk < 4; ++kk) {
                const int arow = wave * 16 + l15;
                const short8 a = *(const short8*)(sbytes + swz(arow, kk * 64 + lkb));
                #pragma unroll
                for (int ct = 0; ct < 8; ++ct) {
                    const int bcol = ct * 16 + l15;
                    const short8 b = *(const short8*)(sbytes + 16384 + swz(bcol, kk * 64 + lkb));
                    acc[ct] = __builtin_amdgcn_mfma_f32_16x16x32_bf16(a, b, acc[ct], 0, 0, 0);
                }
            }
        }

        // epilogue: C/D layout col=lane&15, row=(lane>>4)*4+r (m89-verified); f16 out
        const int orow0 = wave * 16 + (lane >> 4) * 4;
        #pragma unroll
        for (int ct = 0; ct < 8; ++ct) {
            const int col = ct * 16 + l15;
            const float bb = bias[col];
            #pragma unroll
            for (int r = 0; r < 4; ++r)
                hout[(size_t)(orow0 + r) * NA + col] = __float2half(acc[ct][r] + bb);
        }
    } else {
        if (bid == PROJ_BLKS && tid < NA)            // 0.5*Wa in f16 (for x+|x| trick)
            wa16[tid] = __float2half(0.5f * Wa[tid]);

        // value transpose + bf16 convert: 64k x 64d tile
        ushort (*tile)[65] = (ushort (*)[65])smem;
        const int id = bid - PROJ_BLKS;    // 0..511
        const int kt = id & 15;
        const int dt = (id >> 4) & 7;
        const int b  = id >> 7;
        const int k0 = kt * 64, d0 = dt * 64;
        const int tr = tid >> 4, tc4 = (tid & 15) * 4;

        #pragma unroll
        for (int p = 0; p < 4; ++p) {
            const int r = p * 16 + tr;
            const float4 v = *(const float4*)(value + ((size_t)(b * NK + k0 + r)) * ND + d0 + tc4);
            tile[r][tc4 + 0] = f2bf(v.x); tile[r][tc4 + 1] = f2bf(v.y);
            tile[r][tc4 + 2] = f2bf(v.z); tile[r][tc4 + 3] = f2bf(v.w);
        }
        __syncthreads();
        ushort* vo = (ushort*)vt;
        #pragma unroll
        for (int p = 0; p < 4; ++p) {
            const int d = p * 16 + tr;
            ushort4 o;
            o.x = tile[tc4 + 0][d]; o.y = tile[tc4 + 1][d];
            o.z = tile[tc4 + 2][d]; o.w = tile[tc4 + 3][d];
            *(ushort4*)(vo + ((size_t)(b * ND + d0 + d)) * NK + k0 + tc4) = o;
        }
    }
}

// ---------------- Kernel 2: logits + softmax -> score (bf16), packed-f16 math
// logit = sum_a Wa*relu(h1+h2) = sum_a (0.5Wa)*((x)+|x|), x=h1+h2 in f16 pairs:
// v_pk_add_f16 + v_and_b32(0x7FFF7FFF) + v_pk_add_f16 + v_dot2_f32_f16
// = 2 VALU/element (vs 3 scalar f32). h1/Wa reads are wave-uniform -> scalar.
__global__ __launch_bounds__(512) void k_logits_softmax(
    const ushort* __restrict__ h1, const ushort* __restrict__ h2,
    const ushort* __restrict__ wa16, __hip_bfloat16* __restrict__ score)
{
    __shared__ float redm[4][8];
    __shared__ float reds[4][8];
    const int tid = threadIdx.x;
    const int b = blockIdx.x >> 6;
    const int q0 = (blockIdx.x & 63) << 2;

    const uint4* __restrict__ h2b = (const uint4*)(h2 + (size_t)b * NK * NA);
    const uint4* __restrict__ h1g = (const uint4*)(h1 + (size_t)(b * NQ + q0) * NA);
    const uint4* __restrict__ wag = (const uint4*)wa16;

    float lg[4][2];
    #pragma unroll
    for (int c = 0; c < 2; ++c) {
        const int k = tid + c * 512;
        const uint4* row = h2b + (size_t)k * 16;   // 16 uint4 = 128 halfs
        float s0 = 0.f, s1 = 0.f, s2 = 0.f, s3 = 0.f;
        #pragma unroll
        for (int i = 0; i < 16; ++i) {
            const uint4 hv = row[i];               // per-lane (L2)
            const uint4 wv = wag[i];               // uniform -> s_load
            const uint4 p0 = h1g[0 * 16 + i];
            const uint4 p1 = h1g[1 * 16 + i];
            const uint4 p2 = h1g[2 * 16 + i];
            const uint4 p3 = h1g[3 * 16 + i];
            const unsigned hu[4] = {hv.x, hv.y, hv.z, hv.w};
            const unsigned wu[4] = {wv.x, wv.y, wv.z, wv.w};
            const unsigned q0u[4] = {p0.x, p0.y, p0.z, p0.w};
            const unsigned q1u[4] = {p1.x, p1.y, p1.z, p1.w};
            const unsigned q2u[4] = {p2.x, p2.y, p2.z, p2.w};
            const unsigned q3u[4] = {p3.x, p3.y, p3.z, p3.w};
            #pragma unroll
            for (int j = 0; j < 4; ++j) {
                const half2v hh = u2h(hu[j]);
                const half2v ww = u2h(wu[j]);
                {   half2v x = u2h(q0u[j]) + hh;
                    half2v y = x + u2h(h2u(x) & 0x7FFF7FFFu);
                    s0 = __builtin_amdgcn_fdot2(y, ww, s0, false); }
                {   half2v x = u2h(q1u[j]) + hh;
                    half2v y = x + u2h(h2u(x) & 0x7FFF7FFFu);
                    s1 = __builtin_amdgcn_fdot2(y, ww, s1, false); }
                {   half2v x = u2h(q2u[j]) + hh;
                    half2v y = x + u2h(h2u(x) & 0x7FFF7FFFu);
                    s2 = __builtin_amdgcn_fdot2(y, ww, s2, false); }
                {   half2v x = u2h(q3u[j]) + hh;
                    half2v y = x + u2h(h2u(x) & 0x7FFF7FFFu);
                    s3 = __builtin_amdgcn_fdot2(y, ww, s3, false); }
            }
        }
        lg[0][c] = s0; lg[1][c] = s1; lg[2][c] = s2; lg[3][c] = s3;
    }
    // +ba omitted — constant over k, cancels in softmax.

    const int wv_ = tid >> 6, ln = tid & 63;
    float mq[4];
    #pragma unroll
    for (int q = 0; q < 4; ++q) {
        float m = fmaxf(lg[q][0], lg[q][1]);
        for (int off = 32; off > 0; off >>= 1) m = fmaxf(m, __shfl_xor(m, off));
        if (ln == 0) redm[q][wv_] = m;
    }
    __syncthreads();
    #pragma unroll
    for (int q = 0; q < 4; ++q) {
        float m = redm[q][0];
        #pragma unroll
        for (int w = 1; w < 8; ++w) m = fmaxf(m, redm[q][w]);
        mq[q] = m;
    }
    #pragma unroll
    for (int q = 0; q < 4; ++q) {
        float s = 0.f;
        #pragma unroll
        for (int c = 0; c < 2; ++c) { lg[q][c] = __expf(lg[q][c] - mq[q]); s += lg[q][c]; }
        for (int off = 32; off > 0; off >>= 1) s += __shfl_xor(s, off);
        if (ln == 0) reds[q][wv_] = s;
    }
    __syncthreads();
    #pragma unroll
    for (int q = 0; q < 4; ++q) {
        float s = reds[q][0];
        #pragma unroll
        for (int w = 1; w < 8; ++w) s += reds[q][w];
        const float inv = 1.f / s;
        __hip_bfloat16* so = score + (size_t)(b * NQ + q0 + q) * NK + tid;
        #pragma unroll
        for (int c = 0; c < 2; ++c) so[c * 512] = __float2bfloat16(lg[q][c] * inv);
    }
}

// ---------------- Kernel 3: PV via MFMA bf16. BM=16, 512 blocks (2/CU) AND
// ILP=2: K split into two independent 16-deep MFMA chains (k, k+512) summed
// in the epilogue (valid — both chains share the same C/D register layout).
// r6's single 32-deep dependent chain serialized the MFMA pipe; this restores
// r5's ILP while keeping doubled occupancy. No LDS, no barriers.
__global__ __launch_bounds__(256) void k_pv(
    const ushort* __restrict__ sc,   // [B][Q][K] bf16 bits
    const ushort* __restrict__ vt,   // [B][D][K] bf16 bits
    float* __restrict__ out)         // [B][Q][D] f32
{
    const int tid = threadIdx.x;
    const int wave = tid >> 6, lane = tid & 63;
    const int m0 = blockIdx.x * 16;
    const int n0 = blockIdx.y * 64 + wave * 16;
    const int b  = blockIdx.z;
    const int l15 = lane & 15, lk = (lane >> 4) * 8;

    const ushort* arow = sc + (size_t)(b * NQ + m0 + l15) * NK + lk;
    const ushort* brow = vt + (size_t)(b * ND + n0 + l15) * NK + lk;

    f32x4 acc0 = {0.f, 0.f, 0.f, 0.f}, acc1 = {0.f, 0.f, 0.f, 0.f};
    #pragma unroll 4
    for (int k = 0; k < NK / 2; k += 32) {
        const short8 a0 = *(const short8*)(arow + k);
        const short8 v0 = *(const short8*)(brow + k);
        const short8 a1 = *(const short8*)(arow + k + 512);
        const short8 v1 = *(const short8*)(brow + k + 512);
        acc0 = __builtin_amdgcn_mfma_f32_16x16x32_bf16(a0, v0, acc0, 0, 0, 0);
        acc1 = __builtin_amdgcn_mfma_f32_16x16x32_bf16(a1, v1, acc1, 0, 0, 0);
    }

    const int orow = (lane >> 4) * 4;
    #pragma unroll
    for (int r = 0; r < 4; ++r)
        out[(size_t)(b * NQ + m0 + orow + r) * ND + n0 + l15] = acc0[r] + acc1[r];
}

extern "C" void kernel_launch(void* const* d_in, const int* in_sizes, int n_in,
                              void* d_out, int out_size, void* d_ws, size_t ws_size,
                              hipStream_t stream) {
    const float* key   = (const float*)d_in[0];
    const float* query = (const float*)d_in[1];
    const float* value = (const float*)d_in[2];
    const float* Wk    = (const float*)d_in[3];
    const float* bk    = (const float*)d_in[4];
    const float* Wq    = (const float*)d_in[5];
    const float* bq    = (const float*)d_in[6];
    const float* Wa    = (const float*)d_in[7];
    // d_in[8] = ba: cancels in softmax — unused.

    char* ws = (char*)d_ws;
    __half* h1 = (__half*)(ws + OFFB_H1);
    __half* wa16 = (__half*)(ws + OFFB_WA);
    __half* h2 = (__half*)(ws + OFFB_H2);
    __hip_bfloat16* sc = (__hip_bfloat16*)(ws + OFFB_SC);
    __hip_bfloat16* vt = (__hip_bfloat16*)(ws + OFFB_VT);

    k_proj_vt<<<PROJ_BLKS + 512, 256, 0, stream>>>(query, key, value, Wa,
                                                   Wq, bq, Wk, bk, h1, h2, wa16, vt);
    k_logits_softmax<<<256, 512, 0, stream>>>((const ushort*)h1, (const ushort*)h2,
                                              (const ushort*)wa16, sc);
    k_pv<<<dim3(16, 8, 4), 256, 0, stream>>>((const ushort*)sc, (const ushort*)vt,
                                             (float*)d_out);
}

// Round 8
// 60.837 us; speedup vs baseline: 1.0346x; 1.0300x over previous
//
#include <hip/hip_runtime.h>
#include <hip/hip_bf16.h>
#include <math.h>

#define NB 4
#define NQ 256
#define NK 1024
#define ND 512
#define NA 128

// ws layout (bytes)
#define OFFB_H1 0u          // NB*NQ*NA f32 = 512 KB
#define OFFB_H2 524288u     // NB*NK*NA f32 = 2 MB
#define OFFB_SC 2621440u    // NB*NQ*NK bf16 = 2 MB
#define OFFB_VT 4718592u    // NB*ND*NK bf16 = 4 MB

#define PROJ_BLKS 80        // 5120 rows / 64

typedef __attribute__((ext_vector_type(8))) short short8;
typedef __attribute__((ext_vector_type(8))) unsigned short ushort8_t;
typedef __attribute__((ext_vector_type(4))) float f32x4;

static __device__ __forceinline__ ushort f2bf(float x) {
    __hip_bfloat16 h = __float2bfloat16(x);   // RNE
    return *reinterpret_cast<ushort*>(&h);
}

// LDS address swizzle for k1 MFMA staging (write & read identically).
static __device__ __forceinline__ unsigned swz(int row, int o) {
    return (unsigned)(row * 256 + (o ^ ((row & 7) << 4) ^ (((o >> 7) & 1) << 5)));
}

// ---------------- Kernel 1: fused {MFMA projections | value transpose+cvt}
// blocks 0..79: 64 rows x 128 cols of h = X@W^T + b via bf16 MFMA (fp32 out).
// blocks 80..591: vt[b][d][k] = bf16(value[b][k][d]).
__global__ __launch_bounds__(256) void k_proj_vt(
    const float* __restrict__ query, const float* __restrict__ key,
    const float* __restrict__ value,
    const float* __restrict__ Wq, const float* __restrict__ bq,
    const float* __restrict__ Wk, const float* __restrict__ bk,
    float* __restrict__ h1, float* __restrict__ h2,
    __hip_bfloat16* __restrict__ vt)
{
    __shared__ __align__(16) ushort smem[24576];  // 48KB: Xs 16KB @0, Ws 32KB @16384B
    char* sbytes = (char*)smem;
    const int tid = threadIdx.x;
    const int bid = blockIdx.x;

    if (bid < PROJ_BLKS) {
        const int r0 = bid * 64;
        const bool isQ = r0 < NB * NQ;
        const float* X    = isQ ? query + (size_t)r0 * ND : key + (size_t)(r0 - NB * NQ) * ND;
        const float* W    = isQ ? Wq : Wk;
        const float* bias = isQ ? bq : bk;
        float* hout       = isQ ? h1 + (size_t)r0 * NA : h2 + (size_t)(r0 - NB * NQ) * NA;

        const int wave = tid >> 6, lane = tid & 63;
        const int l15 = lane & 15, lkb = (lane >> 4) * 16;   // k byte-offset in frag

        f32x4 acc[8] = {};

        for (int kc = 0; kc < ND; kc += 128) {
            __syncthreads();
            {   // stage X chunk: 64 rows x 128 k, f32 -> bf16, swizzled
                const int row = tid >> 2, kg = (tid & 3) * 32;
                const float* src = X + (size_t)row * ND + kc + kg;
                #pragma unroll
                for (int j = 0; j < 4; ++j) {
                    const float4 v0 = *(const float4*)(src + j * 8);
                    const float4 v1 = *(const float4*)(src + j * 8 + 4);
                    ushort8_t o;
                    o[0] = f2bf(v0.x); o[1] = f2bf(v0.y); o[2] = f2bf(v0.z); o[3] = f2bf(v0.w);
                    o[4] = f2bf(v1.x); o[5] = f2bf(v1.y); o[6] = f2bf(v1.z); o[7] = f2bf(v1.w);
                    *(ushort8_t*)(sbytes + swz(row, kg * 2 + j * 16)) = o;
                }
            }
            {   // stage W chunk: 128 cols x 128 k, f32 -> bf16, swizzled
                const int row = tid >> 1, kg = (tid & 1) * 64;
                const float* src = W + (size_t)row * ND + kc + kg;
                #pragma unroll
                for (int j = 0; j < 8; ++j) {
                    const float4 v0 = *(const float4*)(src + j * 8);
                    const float4 v1 = *(const float4*)(src + j * 8 + 4);
                    ushort8_t o;
                    o[0] = f2bf(v0.x); o[1] = f2bf(v0.y); o[2] = f2bf(v0.z); o[3] = f2bf(v0.w);
                    o[4] = f2bf(v1.x); o[5] = f2bf(v1.y); o[6] = f2bf(v1.z); o[7] = f2bf(v1.w);
                    *(ushort8_t*)(sbytes + 16384 + swz(row, kg * 2 + j * 16)) = o;
                }
            }
            __syncthreads();
            #pragma unroll
            for (int kk = 0; kk < 4; ++kk) {
                const int arow = wave * 16 + l15;
                const short8 a = *(const short8*)(sbytes + swz(arow, kk * 64 + lkb));
                #pragma unroll
                for (int ct = 0; ct < 8; ++ct) {
                    const int bcol = ct * 16 + l15;
                    const short8 b = *(const short8*)(sbytes + 16384 + swz(bcol, kk * 64 + lkb));
                    acc[ct] = __builtin_amdgcn_mfma_f32_16x16x32_bf16(a, b, acc[ct], 0, 0, 0);
                }
            }
        }

        // epilogue: C/D layout col=lane&15, row=(lane>>4)*4+r (m89-verified)
        const int orow0 = wave * 16 + (lane >> 4) * 4;
        #pragma unroll
        for (int ct = 0; ct < 8; ++ct) {
            const int col = ct * 16 + l15;
            const float bb = bias[col];
            #pragma unroll
            for (int r = 0; r < 4; ++r)
                hout[(size_t)(orow0 + r) * NA + col] = acc[ct][r] + bb;
        }
    } else {
        // value transpose + bf16 convert: 64k x 64d tile
        ushort (*tile)[65] = (ushort (*)[65])smem;
        const int id = bid - PROJ_BLKS;    // 0..511
        const int kt = id & 15;
        const int dt = (id >> 4) & 7;
        const int b  = id >> 7;
        const int k0 = kt * 64, d0 = dt * 64;
        const int tr = tid >> 4, tc4 = (tid & 15) * 4;

        #pragma unroll
        for (int p = 0; p < 4; ++p) {
            const int r = p * 16 + tr;
            const float4 v = *(const float4*)(value + ((size_t)(b * NK + k0 + r)) * ND + d0 + tc4);
            tile[r][tc4 + 0] = f2bf(v.x); tile[r][tc4 + 1] = f2bf(v.y);
            tile[r][tc4 + 2] = f2bf(v.z); tile[r][tc4 + 3] = f2bf(v.w);
        }
        __syncthreads();
        ushort* vo = (ushort*)vt;
        #pragma unroll
        for (int p = 0; p < 4; ++p) {
            const int d = p * 16 + tr;
            ushort4 o;
            o.x = tile[tc4 + 0][d]; o.y = tile[tc4 + 1][d];
            o.z = tile[tc4 + 2][d]; o.w = tile[tc4 + 3][d];
            *(ushort4*)(vo + ((size_t)(b * ND + d0 + d)) * NK + k0 + tc4) = o;
        }
    }
}

// ---------------- Kernel 2: logits + softmax -> score (bf16)  [r5-exact]
// block = (b, 4 q-rows), 512 threads. Thread handles k = tid + 512c (c=0..1).
// h1/Wa reads are wave-uniform -> scalar-pipe loads; only per-lane h2 remains.
__global__ __launch_bounds__(512) void k_logits_softmax(
    const float* __restrict__ h1, const float* __restrict__ h2,
    const float* __restrict__ Wa, __hip_bfloat16* __restrict__ score)
{
    __shared__ float redm[4][8];
    __shared__ float reds[4][8];
    const int tid = threadIdx.x;
    const int b = blockIdx.x >> 6;
    const int q0 = (blockIdx.x & 63) << 2;

    const float4* __restrict__ h2b = (const float4*)(h2 + (size_t)b * NK * NA);
    const float4* __restrict__ h1g = (const float4*)(h1 + (size_t)(b * NQ + q0) * NA);
    const float4* __restrict__ wag = (const float4*)Wa;

    float lg[4][2];
    #pragma unroll
    for (int c = 0; c < 2; ++c) {
        const int k = tid + c * 512;
        const float4* row = h2b + (size_t)k * 32;
        float s0 = 0.f, s1 = 0.f, s2 = 0.f, s3 = 0.f;
        #pragma unroll 8
        for (int a4 = 0; a4 < 32; ++a4) {
            const float4 hv = row[a4];         // per-lane (L2)
            const float4 wv = wag[a4];         // wave-uniform -> scalar
            const float4 p0 = h1g[0 * 32 + a4];
            const float4 p1 = h1g[1 * 32 + a4];
            const float4 p2 = h1g[2 * 32 + a4];
            const float4 p3 = h1g[3 * 32 + a4];
            s0 = fmaf(wv.x, fmaxf(p0.x + hv.x, 0.f), s0);
            s0 = fmaf(wv.y, fmaxf(p0.y + hv.y, 0.f), s0);
            s0 = fmaf(wv.z, fmaxf(p0.z + hv.z, 0.f), s0);
            s0 = fmaf(wv.w, fmaxf(p0.w + hv.w, 0.f), s0);
            s1 = fmaf(wv.x, fmaxf(p1.x + hv.x, 0.f), s1);
            s1 = fmaf(wv.y, fmaxf(p1.y + hv.y, 0.f), s1);
            s1 = fmaf(wv.z, fmaxf(p1.z + hv.z, 0.f), s1);
            s1 = fmaf(wv.w, fmaxf(p1.w + hv.w, 0.f), s1);
            s2 = fmaf(wv.x, fmaxf(p2.x + hv.x, 0.f), s2);
            s2 = fmaf(wv.y, fmaxf(p2.y + hv.y, 0.f), s2);
            s2 = fmaf(wv.z, fmaxf(p2.z + hv.z, 0.f), s2);
            s2 = fmaf(wv.w, fmaxf(p2.w + hv.w, 0.f), s2);
            s3 = fmaf(wv.x, fmaxf(p3.x + hv.x, 0.f), s3);
            s3 = fmaf(wv.y, fmaxf(p3.y + hv.y, 0.f), s3);
            s3 = fmaf(wv.z, fmaxf(p3.z + hv.z, 0.f), s3);
            s3 = fmaf(wv.w, fmaxf(p3.w + hv.w, 0.f), s3);
        }
        lg[0][c] = s0; lg[1][c] = s1; lg[2][c] = s2; lg[3][c] = s3;
    }
    // +ba omitted — constant over k, cancels in softmax.

    const int wv_ = tid >> 6, ln = tid & 63;
    float mq[4];
    #pragma unroll
    for (int q = 0; q < 4; ++q) {
        float m = fmaxf(lg[q][0], lg[q][1]);
        for (int off = 32; off > 0; off >>= 1) m = fmaxf(m, __shfl_xor(m, off));
        if (ln == 0) redm[q][wv_] = m;
    }
    __syncthreads();
    #pragma unroll
    for (int q = 0; q < 4; ++q) {
        float m = redm[q][0];
        #pragma unroll
        for (int w = 1; w < 8; ++w) m = fmaxf(m, redm[q][w]);
        mq[q] = m;
    }
    #pragma unroll
    for (int q = 0; q < 4; ++q) {
        float s = 0.f;
        #pragma unroll
        for (int c = 0; c < 2; ++c) { lg[q][c] = __expf(lg[q][c] - mq[q]); s += lg[q][c]; }
        for (int off = 32; off > 0; off >>= 1) s += __shfl_xor(s, off);
        if (ln == 0) reds[q][wv_] = s;
    }
    __syncthreads();
    #pragma unroll
    for (int q = 0; q < 4; ++q) {
        float s = reds[q][0];
        #pragma unroll
        for (int w = 1; w < 8; ++w) s += reds[q][w];
        const float inv = 1.f / s;
        __hip_bfloat16* so = score + (size_t)(b * NQ + q0 + q) * NK + tid;
        #pragma unroll
        for (int c = 0; c < 2; ++c) so[c * 512] = __float2bfloat16(lg[q][c] * inv);
    }
}

// ---------------- Kernel 3: PV via MFMA bf16. BM=32 x BN=32 per block,
// grid (8,16,4)=512 blocks -> 2 blocks/CU (2x the latency hiding of r5's 256)
// while keeping vt duplication at x8 (unchanged vs r5 — the r6 BM16 layout
// doubled it). Each wave owns one 16x16 tile with TWO independent half-K
// MFMA chains (ILP=2, r7-validated). No LDS, no barriers.
__global__ __launch_bounds__(256) void k_pv(
    const ushort* __restrict__ sc,   // [B][Q][K] bf16 bits
    const ushort* __restrict__ vt,   // [B][D][K] bf16 bits
    float* __restrict__ out)         // [B][Q][D] f32
{
    const int tid = threadIdx.x;
    const int wave = tid >> 6, lane = tid & 63;
    const int wr = wave & 1, wc = wave >> 1;
    const int m0 = blockIdx.x * 32 + wr * 16;
    const int n0 = blockIdx.y * 32 + wc * 16;
    const int b  = blockIdx.z;
    const int l15 = lane & 15, lk = (lane >> 4) * 8;

    const ushort* arow = sc + (size_t)(b * NQ + m0 + l15) * NK + lk;
    const ushort* brow = vt + (size_t)(b * ND + n0 + l15) * NK + lk;

    f32x4 acc0 = {0.f, 0.f, 0.f, 0.f}, acc1 = {0.f, 0.f, 0.f, 0.f};
    #pragma unroll 4
    for (int k = 0; k < NK / 2; k += 32) {
        const short8 a0 = *(const short8*)(arow + k);
        const short8 v0 = *(const short8*)(brow + k);
        const short8 a1 = *(const short8*)(arow + k + 512);
        const short8 v1 = *(const short8*)(brow + k + 512);
        acc0 = __builtin_amdgcn_mfma_f32_16x16x32_bf16(a0, v0, acc0, 0, 0, 0);
        acc1 = __builtin_amdgcn_mfma_f32_16x16x32_bf16(a1, v1, acc1, 0, 0, 0);
    }

    const int orow = (lane >> 4) * 4;
    #pragma unroll
    for (int r = 0; r < 4; ++r)
        out[(size_t)(b * NQ + m0 + orow + r) * ND + n0 + l15] = acc0[r] + acc1[r];
}

extern "C" void kernel_launch(void* const* d_in, const int* in_sizes, int n_in,
                              void* d_out, int out_size, void* d_ws, size_t ws_size,
                              hipStream_t stream) {
    const float* key   = (const float*)d_in[0];
    const float* query = (const float*)d_in[1];
    const float* value = (const float*)d_in[2];
    const float* Wk    = (const float*)d_in[3];
    const float* bk    = (const float*)d_in[4];
    const float* Wq    = (const float*)d_in[5];
    const float* bq    = (const float*)d_in[6];
    const float* Wa    = (const float*)d_in[7];
    // d_in[8] = ba: cancels in softmax — unused.

    char* ws = (char*)d_ws;
    float* h1 = (float*)(ws + OFFB_H1);
    float* h2 = (float*)(ws + OFFB_H2);
    __hip_bfloat16* sc = (__hip_bfloat16*)(ws + OFFB_SC);
    __hip_bfloat16* vt = (__hip_bfloat16*)(ws + OFFB_VT);

    k_proj_vt<<<PROJ_BLKS + 512, 256, 0, stream>>>(query, key, value, Wq, bq, Wk, bk,
                                                   h1, h2, vt);
    k_logits_softmax<<<256, 512, 0, stream>>>(h1, h2, Wa, sc);
    k_pv<<<dim3(8, 16, 4), 256, 0, stream>>>((const ushort*)sc, (const ushort*)vt,
                                             (float*)d_out);
}

// Round 9
// 58.217 us; speedup vs baseline: 1.0812x; 1.0450x over previous
//
#include <hip/hip_runtime.h>
#include <hip/hip_bf16.h>
#include <math.h>

#define NB 4
#define NQ 256
#define NK 1024
#define ND 512
#define NA 128

// ws layout (bytes)
#define OFFB_H1 0u          // NB*NQ*NA f32 = 512 KB
#define OFFB_H2 524288u     // NB*NK*NA f32 = 2 MB
#define OFFB_SC 2621440u    // NB*NQ*NK bf16 = 2 MB
#define OFFB_VT 4718592u    // NB*ND*NK bf16 = 4 MB

#define PROJ_BLKS 80        // 5120 rows / 64

typedef __attribute__((ext_vector_type(8))) short short8;
typedef __attribute__((ext_vector_type(8))) unsigned short ushort8_t;
typedef __attribute__((ext_vector_type(4))) float f32x4;

static __device__ __forceinline__ ushort f2bf(float x) {
    __hip_bfloat16 h = __float2bfloat16(x);   // RNE
    return *reinterpret_cast<ushort*>(&h);
}

// LDS address swizzle for k1 MFMA staging (write & read identically).
static __device__ __forceinline__ unsigned swz(int row, int o) {
    return (unsigned)(row * 256 + (o ^ ((row & 7) << 4) ^ (((o >> 7) & 1) << 5)));
}

// ---------------- Kernel 1: fused {MFMA projections | value transpose+cvt}
// blocks 0..79: 64 rows x 128 cols of h = X@W^T + b via bf16 MFMA (fp32 out).
// blocks 80..591: vt[b][d][k] = bf16(value[b][k][d]).
__global__ __launch_bounds__(256) void k_proj_vt(
    const float* __restrict__ query, const float* __restrict__ key,
    const float* __restrict__ value,
    const float* __restrict__ Wq, const float* __restrict__ bq,
    const float* __restrict__ Wk, const float* __restrict__ bk,
    float* __restrict__ h1, float* __restrict__ h2,
    __hip_bfloat16* __restrict__ vt)
{
    __shared__ __align__(16) ushort smem[24576];  // 48KB: Xs 16KB @0, Ws 32KB @16384B
    char* sbytes = (char*)smem;
    const int tid = threadIdx.x;
    const int bid = blockIdx.x;

    if (bid < PROJ_BLKS) {
        const int r0 = bid * 64;
        const bool isQ = r0 < NB * NQ;
        const float* X    = isQ ? query + (size_t)r0 * ND : key + (size_t)(r0 - NB * NQ) * ND;
        const float* W    = isQ ? Wq : Wk;
        const float* bias = isQ ? bq : bk;
        float* hout       = isQ ? h1 + (size_t)r0 * NA : h2 + (size_t)(r0 - NB * NQ) * NA;

        const int wave = tid >> 6, lane = tid & 63;
        const int l15 = lane & 15, lkb = (lane >> 4) * 16;   // k byte-offset in frag

        f32x4 acc[8] = {};

        for (int kc = 0; kc < ND; kc += 128) {
            __syncthreads();
            {   // stage X chunk: 64 rows x 128 k, f32 -> bf16, swizzled
                const int row = tid >> 2, kg = (tid & 3) * 32;
                const float* src = X + (size_t)row * ND + kc + kg;
                #pragma unroll
                for (int j = 0; j < 4; ++j) {
                    const float4 v0 = *(const float4*)(src + j * 8);
                    const float4 v1 = *(const float4*)(src + j * 8 + 4);
                    ushort8_t o;
                    o[0] = f2bf(v0.x); o[1] = f2bf(v0.y); o[2] = f2bf(v0.z); o[3] = f2bf(v0.w);
                    o[4] = f2bf(v1.x); o[5] = f2bf(v1.y); o[6] = f2bf(v1.z); o[7] = f2bf(v1.w);
                    *(ushort8_t*)(sbytes + swz(row, kg * 2 + j * 16)) = o;
                }
            }
            {   // stage W chunk: 128 cols x 128 k, f32 -> bf16, swizzled
                const int row = tid >> 1, kg = (tid & 1) * 64;
                const float* src = W + (size_t)row * ND + kc + kg;
                #pragma unroll
                for (int j = 0; j < 8; ++j) {
                    const float4 v0 = *(const float4*)(src + j * 8);
                    const float4 v1 = *(const float4*)(src + j * 8 + 4);
                    ushort8_t o;
                    o[0] = f2bf(v0.x); o[1] = f2bf(v0.y); o[2] = f2bf(v0.z); o[3] = f2bf(v0.w);
                    o[4] = f2bf(v1.x); o[5] = f2bf(v1.y); o[6] = f2bf(v1.z); o[7] = f2bf(v1.w);
                    *(ushort8_t*)(sbytes + 16384 + swz(row, kg * 2 + j * 16)) = o;
                }
            }
            __syncthreads();
            #pragma unroll
            for (int kk = 0; kk < 4; ++kk) {
                const int arow = wave * 16 + l15;
                const short8 a = *(const short8*)(sbytes + swz(arow, kk * 64 + lkb));
                #pragma unroll
                for (int ct = 0; ct < 8; ++ct) {
                    const int bcol = ct * 16 + l15;
                    const short8 b = *(const short8*)(sbytes + 16384 + swz(bcol, kk * 64 + lkb));
                    acc[ct] = __builtin_amdgcn_mfma_f32_16x16x32_bf16(a, b, acc[ct], 0, 0, 0);
                }
            }
        }

        // epilogue: C/D layout col=lane&15, row=(lane>>4)*4+r (m89-verified)
        const int orow0 = wave * 16 + (lane >> 4) * 4;
        #pragma unroll
        for (int ct = 0; ct < 8; ++ct) {
            const int col = ct * 16 + l15;
            const float bb = bias[col];
            #pragma unroll
            for (int r = 0; r < 4; ++r)
                hout[(size_t)(orow0 + r) * NA + col] = acc[ct][r] + bb;
        }
    } else {
        // value transpose + bf16 convert: 64k x 64d tile
        ushort (*tile)[65] = (ushort (*)[65])smem;
        const int id = bid - PROJ_BLKS;    // 0..511
        const int kt = id & 15;
        const int dt = (id >> 4) & 7;
        const int b  = id >> 7;
        const int k0 = kt * 64, d0 = dt * 64;
        const int tr = tid >> 4, tc4 = (tid & 15) * 4;

        #pragma unroll
        for (int p = 0; p < 4; ++p) {
            const int r = p * 16 + tr;
            const float4 v = *(const float4*)(value + ((size_t)(b * NK + k0 + r)) * ND + d0 + tc4);
            tile[r][tc4 + 0] = f2bf(v.x); tile[r][tc4 + 1] = f2bf(v.y);
            tile[r][tc4 + 2] = f2bf(v.z); tile[r][tc4 + 3] = f2bf(v.w);
        }
        __syncthreads();
        ushort* vo = (ushort*)vt;
        #pragma unroll
        for (int p = 0; p < 4; ++p) {
            const int d = p * 16 + tr;
            ushort4 o;
            o.x = tile[tc4 + 0][d]; o.y = tile[tc4 + 1][d];
            o.z = tile[tc4 + 2][d]; o.w = tile[tc4 + 3][d];
            *(ushort4*)(vo + ((size_t)(b * ND + d0 + d)) * NK + k0 + tc4) = o;
        }
    }
}

// ---------------- Kernel 2: logits + softmax -> score (bf16)  [r5-exact]
__global__ __launch_bounds__(512) void k_logits_softmax(
    const float* __restrict__ h1, const float* __restrict__ h2,
    const float* __restrict__ Wa, __hip_bfloat16* __restrict__ score)
{
    __shared__ float redm[4][8];
    __shared__ float reds[4][8];
    const int tid = threadIdx.x;
    const int b = blockIdx.x >> 6;
    const int q0 = (blockIdx.x & 63) << 2;

    const float4* __restrict__ h2b = (const float4*)(h2 + (size_t)b * NK * NA);
    const float4* __restrict__ h1g = (const float4*)(h1 + (size_t)(b * NQ + q0) * NA);
    const float4* __restrict__ wag = (const float4*)Wa;

    float lg[4][2];
    #pragma unroll
    for (int c = 0; c < 2; ++c) {
        const int k = tid + c * 512;
        const float4* row = h2b + (size_t)k * 32;
        float s0 = 0.f, s1 = 0.f, s2 = 0.f, s3 = 0.f;
        #pragma unroll 8
        for (int a4 = 0; a4 < 32; ++a4) {
            const float4 hv = row[a4];         // per-lane (L2)
            const float4 wv = wag[a4];         // wave-uniform -> scalar
            const float4 p0 = h1g[0 * 32 + a4];
            const float4 p1 = h1g[1 * 32 + a4];
            const float4 p2 = h1g[2 * 32 + a4];
            const float4 p3 = h1g[3 * 32 + a4];
            s0 = fmaf(wv.x, fmaxf(p0.x + hv.x, 0.f), s0);
            s0 = fmaf(wv.y, fmaxf(p0.y + hv.y, 0.f), s0);
            s0 = fmaf(wv.z, fmaxf(p0.z + hv.z, 0.f), s0);
            s0 = fmaf(wv.w, fmaxf(p0.w + hv.w, 0.f), s0);
            s1 = fmaf(wv.x, fmaxf(p1.x + hv.x, 0.f), s1);
            s1 = fmaf(wv.y, fmaxf(p1.y + hv.y, 0.f), s1);
            s1 = fmaf(wv.z, fmaxf(p1.z + hv.z, 0.f), s1);
            s1 = fmaf(wv.w, fmaxf(p1.w + hv.w, 0.f), s1);
            s2 = fmaf(wv.x, fmaxf(p2.x + hv.x, 0.f), s2);
            s2 = fmaf(wv.y, fmaxf(p2.y + hv.y, 0.f), s2);
            s2 = fmaf(wv.z, fmaxf(p2.z + hv.z, 0.f), s2);
            s2 = fmaf(wv.w, fmaxf(p2.w + hv.w, 0.f), s2);
            s3 = fmaf(wv.x, fmaxf(p3.x + hv.x, 0.f), s3);
            s3 = fmaf(wv.y, fmaxf(p3.y + hv.y, 0.f), s3);
            s3 = fmaf(wv.z, fmaxf(p3.z + hv.z, 0.f), s3);
            s3 = fmaf(wv.w, fmaxf(p3.w + hv.w, 0.f), s3);
        }
        lg[0][c] = s0; lg[1][c] = s1; lg[2][c] = s2; lg[3][c] = s3;
    }
    // +ba omitted — constant over k, cancels in softmax.

    const int wv_ = tid >> 6, ln = tid & 63;
    float mq[4];
    #pragma unroll
    for (int q = 0; q < 4; ++q) {
        float m = fmaxf(lg[q][0], lg[q][1]);
        for (int off = 32; off > 0; off >>= 1) m = fmaxf(m, __shfl_xor(m, off));
        if (ln == 0) redm[q][wv_] = m;
    }
    __syncthreads();
    #pragma unroll
    for (int q = 0; q < 4; ++q) {
        float m = redm[q][0];
        #pragma unroll
        for (int w = 1; w < 8; ++w) m = fmaxf(m, redm[q][w]);
        mq[q] = m;
    }
    #pragma unroll
    for (int q = 0; q < 4; ++q) {
        float s = 0.f;
        #pragma unroll
        for (int c = 0; c < 2; ++c) { lg[q][c] = __expf(lg[q][c] - mq[q]); s += lg[q][c]; }
        for (int off = 32; off > 0; off >>= 1) s += __shfl_xor(s, off);
        if (ln == 0) reds[q][wv_] = s;
    }
    __syncthreads();
    #pragma unroll
    for (int q = 0; q < 4; ++q) {
        float s = reds[q][0];
        #pragma unroll
        for (int w = 1; w < 8; ++w) s += reds[q][w];
        const float inv = 1.f / s;
        __hip_bfloat16* so = score + (size_t)(b * NQ + q0 + q) * NK + tid;
        #pragma unroll
        for (int c = 0; c < 2; ++c) so[c * 512] = __float2bfloat16(lg[q][c] * inv);
    }
}

// ---------------- Kernel 3: PV via MFMA bf16. r5 shape (BM=32, BN=64, 4 waves,
// each wave 16x32 with 2 independent accumulator chains) + XCD-AWARE 1D remap:
// blocks dispatch round-robin to XCDs, so xcd = bid&7 owns ONE fixed n-tile.
// Each XCD then reads all sc (2MB) + its vt panel (512KB) = 2.5MB < 4MB L2 ->
// L2-resident after first touch; L3 traffic ~48MB -> ~20MB (k3 is L3-BW-bound
// per the r5/r8/r6 traffic-vs-time fit: +1 us per +9 MB).
__global__ __launch_bounds__(256) void k_pv(
    const ushort* __restrict__ sc,   // [B][Q][K] bf16 bits
    const ushort* __restrict__ vt,   // [B][D][K] bf16 bits
    float* __restrict__ out)         // [B][Q][D] f32
{
    const int bid = blockIdx.x;      // 0..255
    const int y   = bid & 7;         // n-tile (one per XCD)
    const int loc = bid >> 3;        // 0..31
    const int x   = loc & 7;         // m-tile
    const int b   = loc >> 3;        // batch

    const int tid = threadIdx.x;
    const int wave = tid >> 6, lane = tid & 63;
    const int wr = wave >> 1, wc = wave & 1;
    const int m0 = x * 32 + wr * 16;
    const int n0 = y * 64 + wc * 32;
    const int l15 = lane & 15, lk = (lane >> 4) * 8;

    const ushort* arow  = sc + (size_t)(b * NQ + m0 + l15) * NK + lk;
    const ushort* b0row = vt + (size_t)(b * ND + n0 + l15) * NK + lk;
    const ushort* b1row = vt + (size_t)(b * ND + n0 + 16 + l15) * NK + lk;

    f32x4 acc0 = {0.f, 0.f, 0.f, 0.f}, acc1 = {0.f, 0.f, 0.f, 0.f};
    #pragma unroll 4
    for (int k = 0; k < NK; k += 32) {
        const short8 a  = *(const short8*)(arow + k);
        const short8 v0 = *(const short8*)(b0row + k);
        const short8 v1 = *(const short8*)(b1row + k);
        acc0 = __builtin_amdgcn_mfma_f32_16x16x32_bf16(a, v0, acc0, 0, 0, 0);
        acc1 = __builtin_amdgcn_mfma_f32_16x16x32_bf16(a, v1, acc1, 0, 0, 0);
    }

    const int orow = (lane >> 4) * 4;
    #pragma unroll
    for (int r = 0; r < 4; ++r) {
        float* po = out + (size_t)(b * NQ + m0 + orow + r) * ND + n0;
        po[l15]      = acc0[r];
        po[16 + l15] = acc1[r];
    }
}

extern "C" void kernel_launch(void* const* d_in, const int* in_sizes, int n_in,
                              void* d_out, int out_size, void* d_ws, size_t ws_size,
                              hipStream_t stream) {
    const float* key   = (const float*)d_in[0];
    const float* query = (const float*)d_in[1];
    const float* value = (const float*)d_in[2];
    const float* Wk    = (const float*)d_in[3];
    const float* bk    = (const float*)d_in[4];
    const float* Wq    = (const float*)d_in[5];
    const float* bq    = (const float*)d_in[6];
    const float* Wa    = (const float*)d_in[7];
    // d_in[8] = ba: cancels in softmax — unused.

    char* ws = (char*)d_ws;
    float* h1 = (float*)(ws + OFFB_H1);
    float* h2 = (float*)(ws + OFFB_H2);
    __hip_bfloat16* sc = (__hip_bfloat16*)(ws + OFFB_SC);
    __hip_bfloat16* vt = (__hip_bfloat16*)(ws + OFFB_VT);

    k_proj_vt<<<PROJ_BLKS + 512, 256, 0, stream>>>(query, key, value, Wq, bq, Wk, bk,
                                                   h1, h2, vt);
    k_logits_softmax<<<256, 512, 0, stream>>>(h1, h2, Wa, sc);
    k_pv<<<256, 256, 0, stream>>>((const ushort*)sc, (const ushort*)vt,
                                  (float*)d_out);
}